// Round 9
// baseline (218.658 us; speedup 1.0000x reference)
//
#include <hip/hip_runtime.h>
#include <hip/hip_bf16.h>

typedef __attribute__((ext_vector_type(4))) float f32x4;
typedef __attribute__((ext_vector_type(16))) float f32x16;
typedef __attribute__((ext_vector_type(8))) short bf16x8;
typedef __attribute__((ext_vector_type(4))) unsigned short u16x4;
typedef __attribute__((ext_vector_type(8))) unsigned short u16x8;
typedef __attribute__((ext_vector_type(2))) unsigned int u32x2;

#define MFMA16(a, b, c) __builtin_amdgcn_mfma_f32_16x16x32_bf16((a), (b), (c), 0, 0, 0)
#define MFMA32(a, b, c) __builtin_amdgcn_mfma_f32_32x32x16_bf16((a), (b), (c), 0, 0, 0)

static __device__ __forceinline__ unsigned short f2bf(float f) {
    union { float f; unsigned int u; } v; v.f = f;
    unsigned int r = v.u + 0x7FFFu + ((v.u >> 16) & 1u);  // RNE
    return (unsigned short)(r >> 16);
}
// HW packed f32->bf16 (T12 recipe; src0 -> low half)
static __device__ __forceinline__ unsigned int pk2(float x, float y) {
    unsigned int r;
    asm("v_cvt_pk_bf16_f32 %0, %1, %2" : "=v"(r) : "v"(x), "v"(y));
    return r;
}
static __device__ __forceinline__ float bf2f(unsigned short u) {
    return __uint_as_float((unsigned int)u << 16);
}

static __device__ __forceinline__ void gload_lds16(const void* g, void* l) {
    __builtin_amdgcn_global_load_lds(
        (const __attribute__((address_space(1))) void*)g,
        (__attribute__((address_space(3))) void*)l, 16, 0, 0);
}

// ---------------------------------------------------------------------------
// prepass: fused activation convert (fp32->bf16) + weight transpose.
// ---------------------------------------------------------------------------
__global__ __launch_bounds__(256) void prepass(
    const float* __restrict__ q, const float* __restrict__ k,
    const float* __restrict__ v, const float* __restrict__ Wq,
    const float* __restrict__ Wk, const float* __restrict__ Wv,
    const float* __restrict__ Wo, unsigned short* __restrict__ qc,
    unsigned short* __restrict__ kc, unsigned short* __restrict__ vc,
    unsigned short* __restrict__ Wt, unsigned short* __restrict__ Wot) {
    __shared__ unsigned short T[64][65];
    const int id = blockIdx.x, t = threadIdx.x;
    if (id < 6144) {
        const int z = id >> 11;  // /2048
        const float* src = z == 0 ? q : (z == 1 ? k : v);
        unsigned short* dst = z == 0 ? qc : (z == 1 ? kc : vc);
        size_t off = ((size_t)(id & 2047) * 256 + t) * 8;
        f32x4 a = *(const f32x4*)&src[off];
        f32x4 b = *(const f32x4*)&src[off + 4];
        union { unsigned int u[4]; u16x8 v; } o;
        o.u[0] = pk2(a[0], a[1]); o.u[1] = pk2(a[2], a[3]);
        o.u[2] = pk2(b[0], b[1]); o.u[3] = pk2(b[2], b[3]);
        *(u16x8*)&dst[off] = o.v;
    } else {
        int r = id - 6144;           // 0..1023
        const int z = r >> 8; r &= 255;
        const float* W = z == 0 ? Wq : (z == 1 ? Wk : (z == 2 ? Wv : Wo));
        unsigned short* Wd = z < 3 ? (Wt + (size_t)z * 1024 * 1024) : Wot;
        const int k0 = (r >> 4) * 64, n0 = (r & 15) * 64;
        const int rl = t >> 4, c4 = (t & 15) * 4;
#pragma unroll
        for (int i = 0; i < 4; ++i) {
            f32x4 vv = *(const f32x4*)&W[(size_t)(k0 + rl + 16 * i) * 1024 + n0 + c4];
#pragma unroll
            for (int j = 0; j < 4; ++j) T[rl + 16 * i][c4 + j] = f2bf(vv[j]);
        }
        __syncthreads();
#pragma unroll
        for (int i = 0; i < 4; ++i) {
            u16x4 o;
#pragma unroll
            for (int j = 0; j < 4; ++j) o[j] = T[c4 + j][rl + 16 * i];
            *(u16x4*)&Wd[(size_t)(n0 + rl + 16 * i) * 1024 + k0 + c4] = o;
        }
    }
}

// ---------------------------------------------------------------------------
// gemm_fast: 2-phase double-buffered m97 structure, XCD-chunked 1-D grid.
// SWZ=0 (QKV, BM=BN=128): 32Mx24N tiles, 16 chunks of 8Mx6N, 2 chunks/XCD.
// SWZ=1 (out, generic): XCD owns (MT/8) M-tile band x all N (L2-resident).
// ---------------------------------------------------------------------------
template <bool OUT_BF16, int BM, int BN, int SWZ, int MINW>
__global__ __launch_bounds__(256, MINW) void gemm_fast(
    const unsigned short* __restrict__ A0, const unsigned short* __restrict__ A1,
    const unsigned short* __restrict__ A2, const unsigned short* __restrict__ Wt,
    const float* __restrict__ b0, const float* __restrict__ b1,
    const float* __restrict__ b2, void* __restrict__ Outv, int ldo) {
    constexpr int MF = BM / 32;  // m-frags per wave
    constexpr int NF = BN / 32;  // n-frags per wave
    __shared__ __align__(16) unsigned short As[2][BM * 32];
    __shared__ __align__(16) unsigned short Bs[2][BN * 32];

    const int t = threadIdx.x;
    const int w = t >> 6, lane = t & 63;  // w in [0,4)
    const int wr = w >> 1, wc = w & 1;
    const int g = lane >> 4, r15 = lane & 15;

    const int id = blockIdx.x;
    int bm, bn;
    if (SWZ == 0) {
        const int xcd = id & 7, local = id >> 3;          // local in [0,96)
        const int half = local >= 48 ? 1 : 0;
        const int ww = local - half * 48;                 // [0,48)
        const int gg = xcd * 2 + half;                    // chunk [0,16)
        bm = ((gg >> 2) * 8 + (ww & 7)) * BM;             // mt in [0,32)
        bn = ((gg & 3) * 6 + (ww >> 3)) * BN;             // nt in [0,24)
    } else {
        constexpr int MPX = (4096 / BM) / 8;              // M-tiles per XCD
        const int xcd = id & 7, local = id >> 3;
        bm = (xcd * MPX + (local % MPX)) * BM;
        bn = (local / MPX) * BN;
    }
    const int msel = bn >> 10;
    const unsigned short* A = msel == 0 ? A0 : (msel == 1 ? A1 : A2);
    const float* bias = msel == 0 ? b0 : (msel == 1 ? b1 : b2);
    const int l4 = lane >> 2, c8 = (lane & 3) * 8;

    f32x4 acc[MF][NF];
#pragma unroll
    for (int m = 0; m < MF; ++m)
#pragma unroll
        for (int n = 0; n < NF; ++n) acc[m][n] = (f32x4){0.f, 0.f, 0.f, 0.f};

#define G_STAGE(BUF, KT)                                                          \
    {                                                                             \
        gload_lds16(&A[(size_t)(bm + 16 * w + l4) * 1024 + (KT) + c8],            \
                    &As[BUF][w * 512]);                                           \
        if (BM == 128)                                                            \
            gload_lds16(&A[(size_t)(bm + 16 * (w + 4) + l4) * 1024 + (KT) + c8],  \
                        &As[BUF][(w + 4) * 512]);                                 \
        gload_lds16(&Wt[(size_t)(bn + 16 * w + l4) * 1024 + (KT) + c8],           \
                    &Bs[BUF][(w * 512) % (BN * 32)]);                             \
        if (BN == 128)                                                            \
            gload_lds16(&Wt[(size_t)(bn + 16 * (w + 4) + l4) * 1024 + (KT) + c8], \
                        &Bs[BUF][((w + 4) * 512) % (BN * 32)]);                   \
    }

    G_STAGE(0, 0);
    __syncthreads();

    int cur = 0;
    for (int kt = 0; kt < 1024; kt += 32) {
        if (kt < 992) G_STAGE(cur ^ 1, kt + 32);
        bf16x8 af[MF], bfr[NF];
#pragma unroll
        for (int m = 0; m < MF; ++m)
            af[m] = *(const bf16x8*)&As[cur][(wr * (BM / 2) + m * 16 + r15) * 32 + g * 8];
#pragma unroll
        for (int n = 0; n < NF; ++n)
            bfr[n] = *(const bf16x8*)&Bs[cur][(wc * (BN / 2) + n * 16 + r15) * 32 + g * 8];
        __builtin_amdgcn_s_setprio(1);
#pragma unroll
        for (int m = 0; m < MF; ++m)
#pragma unroll
            for (int n = 0; n < NF; ++n)
                acc[m][n] = MFMA16(af[m], bfr[n], acc[m][n]);
        __builtin_amdgcn_s_setprio(0);
        __syncthreads();
        cur ^= 1;
    }
#undef G_STAGE

    float* Of = (float*)Outv;
    unsigned short* Ob = (unsigned short*)Outv;
#pragma unroll
    for (int n = 0; n < NF; ++n) {
        int col = bn + wc * (BN / 2) + n * 16 + r15;
        float bv = bias[col & 1023];
#pragma unroll
        for (int m = 0; m < MF; ++m) {
#pragma unroll
            for (int r = 0; r < 4; ++r) {
                int row = bm + wr * (BM / 2) + m * 16 + g * 4 + r;
                float val = acc[m][n][r] + bv;
                if (OUT_BF16)
                    Ob[(size_t)row * ldo + col] = f2bf(val);
                else
                    Of[(size_t)row * ldo + col] = val;
            }
        }
    }
}

// ---------------------------------------------------------------------------
// attn32: swapped-operand 32x32 flash attention, BLOCK-LEVEL KV split.
// Round-4 proven inner loop; each block covers 512 keys (half = sid&1),
// writes self-normalized partial O (bf16) + (m,l); attn_merge combines.
// Grid 1024. __launch_bounds__(256,2): natural regalloc (~76 VGPR <= 128),
// HW occupancy comes from LDS fit (4 x 40KB = 160KB/CU) — NOT a regalloc cap
// (the (256,4) cap was what caused round-5/6 spills).
// ---------------------------------------------------------------------------
__global__ __launch_bounds__(256, 2) void attn32_kernel(
    const unsigned short* __restrict__ Q, const unsigned short* __restrict__ K,
    const unsigned short* __restrict__ V, unsigned short* __restrict__ Opart,
    float* __restrict__ ML, int ld) {
    __shared__ __align__(16) unsigned short Kls[2][64 * 80];
    __shared__ __align__(16) unsigned short Vls[2][64 * 80];

    const int t = threadIdx.x;
    const int w = t >> 6, lane = t & 63;
    const int q5 = lane & 31, hi = lane >> 5;

    // XCD swizzle (1024 blocks, bijective); 16 consecutive sid per (b,h).
    const int id = blockIdx.x;
    const int sid = (id & 7) * 128 + (id >> 3);
    const int bh = sid >> 4, sub = sid & 15;
    const int qb = sub >> 1, half = sub & 1;
    const int b = bh >> 4, h = bh & 15;
    const int brow = b * 1024;
    const int q0 = qb * 128;
    const int kv0 = half * 512;

    const float c2 = 0.18033688f;  // (1/8) * log2(e)

    const unsigned short* Qrow = Q + (size_t)(brow + q0 + w * 32 + q5) * ld + h * 64;
    bf16x8 qreg[8];
#pragma unroll
    for (int j = 0; j < 8; ++j) qreg[j] = *(const bf16x8*)&Qrow[8 * j];
    bf16x8 qsel[4];
#pragma unroll
    for (int kk = 0; kk < 4; ++kk) qsel[kk] = hi ? qreg[2 * kk + 1] : qreg[2 * kk];

    // staging roles: K by (row, 16B slot); V by (key-pair, d-chunk of 8)
    const int krow = t >> 2, kpart = t & 3;
    const int vp = t & 31, vdc = t >> 5;
    const unsigned short* Kg = K + h * 64;
    const unsigned short* Vg = V + h * 64;

    u16x8 kr0, kr1, vr0, vr1;
#define STG_LOAD(KT)                                                            \
    {                                                                           \
        size_t kro = (size_t)(brow + (KT) + krow) * ld;                         \
        kr0 = *(const u16x8*)&Kg[kro + kpart * 8];                              \
        kr1 = *(const u16x8*)&Kg[kro + kpart * 8 + 32];                         \
        size_t vro = (size_t)(brow + (KT) + 2 * vp) * ld;                       \
        vr0 = *(const u16x8*)&Vg[vro + vdc * 8];                                \
        vr1 = *(const u16x8*)&Vg[vro + ld + vdc * 8];                           \
    }
#define STG_WRITE(BUF)                                                          \
    {                                                                           \
        char* kb_ = (char*)Kls[BUF];                                            \
        int tg_ = (krow & 7) << 4;                                              \
        *(u16x8*)(kb_ + krow * 160 + ((kpart * 16) ^ tg_)) = kr0;               \
        *(u16x8*)(kb_ + krow * 160 + (((kpart + 4) * 16) ^ tg_)) = kr1;         \
        char* vb_ = (char*)Vls[BUF];                                            \
        _Pragma("unroll") for (int j_ = 0; j_ < 8; ++j_) {                      \
            int d_ = vdc * 8 + j_;                                              \
            unsigned int pk_ = (unsigned int)(unsigned short)vr0[j_] |          \
                               ((unsigned int)(unsigned short)vr1[j_] << 16);   \
            *(unsigned int*)(vb_ + d_ * 160 + ((vp * 4) ^ ((d_ & 7) << 4)))     \
                = pk_;                                                          \
        }                                                                       \
    }

    f32x16 acc0 = {}, acc1 = {};
    float mrun = -1e30f, lrun = 0.f;

    STG_LOAD(kv0);
    STG_WRITE(0);
    __syncthreads();

    int cur = 0;
    for (int tile = 0; tile < 8; ++tile) {
        const bool more = tile < 7;
        if (more) STG_LOAD(kv0 + tile * 64 + 64);

        // ---- QK^T
        char* kb = (char*)Kls[cur];
        f32x16 st0 = {}, st1 = {};
        {
            const int tg0 = (q5 & 7) << 4;
            char* kp0 = kb + q5 * 160;
            char* kp1 = kb + (q5 + 32) * 160;
            __builtin_amdgcn_s_setprio(1);
#pragma unroll
            for (int kk = 0; kk < 4; ++kk) {
                int so = ((2 * kk + hi) * 16) ^ tg0;
                bf16x8 kf0 = *(const bf16x8*)(kp0 + so);
                bf16x8 kf1 = *(const bf16x8*)(kp1 + so);
                st0 = MFMA32(kf0, qsel[kk], st0);
                st1 = MFMA32(kf1, qsel[kk], st1);
            }
            __builtin_amdgcn_s_setprio(0);
        }

        // ---- online softmax with defer-max (T13)
        float mloc = fmaxf(st0[0], st0[1]);
#pragma unroll
        for (int r = 2; r < 16; ++r) mloc = fmaxf(mloc, st0[r]);
#pragma unroll
        for (int r = 0; r < 16; ++r) mloc = fmaxf(mloc, st1[r]);
        mloc = fmaxf(mloc, __shfl_xor(mloc, 32));
        if (!__all(mloc - mrun <= 64.f)) {
            float mnew = fmaxf(mrun, mloc);
            float sf = exp2f((mrun - mnew) * c2);
            mrun = mnew;
            lrun *= sf;
#pragma unroll
            for (int r = 0; r < 16; ++r) { acc0[r] *= sf; acc1[r] *= sf; }
        }
        float mneg = -mrun * c2;
        float rs = 0.f;
#pragma unroll
        for (int r = 0; r < 16; ++r) {
            st0[r] = exp2f(fmaf(st0[r], c2, mneg));
            rs += st0[r];
        }
#pragma unroll
        for (int r = 0; r < 16; ++r) {
            st1[r] = exp2f(fmaf(st1[r], c2, mneg));
            rs += st1[r];
        }
        rs += __shfl_xor(rs, 32);
        lrun += rs;

        // ---- P^T pack (cvt_pk) + PV (O^T += V^T * P^T)
        char* vb = (char*)Vls[cur];
        const int tgv = (q5 & 7) << 4;
        char* vp0 = vb + q5 * 160;
        char* vp1 = vb + (q5 + 32) * 160;
        __builtin_amdgcn_s_setprio(1);
#define PV_HALF(ST, CT)                                                         \
    _Pragma("unroll") for (int ks = 0; ks < 2; ++ks) {                          \
        unsigned int a0 = pk2(ST[8 * ks + 0], ST[8 * ks + 1]);                  \
        unsigned int a1 = pk2(ST[8 * ks + 2], ST[8 * ks + 3]);                  \
        unsigned int a2 = pk2(ST[8 * ks + 4], ST[8 * ks + 5]);                  \
        unsigned int a3 = pk2(ST[8 * ks + 6], ST[8 * ks + 7]);                  \
        unsigned int x0 = __shfl_xor(a0, 32), x1 = __shfl_xor(a1, 32);          \
        unsigned int x2 = __shfl_xor(a2, 32), x3 = __shfl_xor(a3, 32);          \
        union { unsigned int u[4]; bf16x8 v; } pfu;                             \
        pfu.u[0] = hi ? x2 : a0;                                                \
        pfu.u[1] = hi ? x3 : a1;                                                \
        pfu.u[2] = hi ? a2 : x0;                                                \
        pfu.u[3] = hi ? a3 : x1;                                                \
        int co = ((32 * (2 * (CT) + ks) + 16 * hi)) ^ tgv;                      \
        bf16x8 vf0 = *(const bf16x8*)(vp0 + co);                                \
        bf16x8 vf1 = *(const bf16x8*)(vp1 + co);                                \
        acc0 = MFMA32(vf0, pfu.v, acc0);                                        \
        acc1 = MFMA32(vf1, pfu.v, acc1);                                        \
    }
        PV_HALF(st0, 0);
        PV_HALF(st1, 1);
        __builtin_amdgcn_s_setprio(0);

        if (more) STG_WRITE(cur ^ 1);
        __syncthreads();
        cur ^= 1;
    }

    // ---- epilogue: self-normalized partial + (m,l)
    const int grow = brow + q0 + w * 32 + q5;
    const float inv = 1.0f / lrun;
    unsigned short* Orow =
        Opart + (size_t)half * 4194304 + (size_t)grow * 1024 + h * 64;
#pragma unroll
    for (int k = 0; k < 4; ++k) {
        int d0 = 8 * k + 4 * hi;
        u32x2 pa, pb;
        pa[0] = pk2(acc0[4 * k + 0] * inv, acc0[4 * k + 1] * inv);
        pa[1] = pk2(acc0[4 * k + 2] * inv, acc0[4 * k + 3] * inv);
        *(u32x2*)&Orow[d0] = pa;
        pb[0] = pk2(acc1[4 * k + 0] * inv, acc1[4 * k + 1] * inv);
        pb[1] = pk2(acc1[4 * k + 2] * inv, acc1[4 * k + 3] * inv);
        *(u32x2*)&Orow[32 + d0] = pb;
    }
    if (hi == 0)
        ((float2*)ML)[half * 65536 + grow * 16 + h] = make_float2(mrun, lrun);
#undef STG_LOAD
#undef STG_WRITE
#undef PV_HALF
}

// ---------------------------------------------------------------------------
// attn_merge: LSE-combine the two KV-half partials. 8 threads per (row,head).
// ---------------------------------------------------------------------------
__global__ __launch_bounds__(256) void attn_merge(
    const unsigned short* __restrict__ Opart, const float* __restrict__ ML,
    unsigned short* __restrict__ Omg) {
    const float c2 = 0.18033688f;
    const int gid = blockIdx.x * 256 + threadIdx.x;
    const int pair = gid >> 3;   // row*16 + h
    const int dp = gid & 7;
    const int row = pair >> 4, h = pair & 15;
    const float2 ml0 = ((const float2*)ML)[pair];
    const float2 ml1 = ((const float2*)ML)[65536 + pair];
    float mn = fmaxf(ml0.x, ml1.x);
    float w0 = ml0.y * exp2f((ml0.x - mn) * c2);
    float w1 = ml1.y * exp2f((ml1.x - mn) * c2);
    float inv = 1.0f / (w0 + w1);
    w0 *= inv; w1 *= inv;
    size_t off = (size_t)row * 1024 + h * 64 + dp * 8;
    u16x8 a = *(const u16x8*)&Opart[off];
    u16x8 b = *(const u16x8*)&Opart[4194304 + off];
    union { unsigned int u[4]; u16x8 v; } o;
#pragma unroll
    for (int j = 0; j < 4; ++j)
        o.u[j] = pk2(bf2f(a[2 * j]) * w0 + bf2f(b[2 * j]) * w1,
                     bf2f(a[2 * j + 1]) * w0 + bf2f(b[2 * j + 1]) * w1);
    *(u16x8*)&Omg[off] = o.v;
}

extern "C" void kernel_launch(void* const* d_in, const int* in_sizes, int n_in,
                              void* d_out, int out_size, void* d_ws, size_t ws_size,
                              hipStream_t stream) {
    const float* q  = (const float*)d_in[0];
    const float* k  = (const float*)d_in[1];
    const float* v  = (const float*)d_in[2];
    const float* Wq = (const float*)d_in[3];
    const float* bq = (const float*)d_in[4];
    const float* Wk = (const float*)d_in[5];
    const float* bk = (const float*)d_in[6];
    const float* Wv = (const float*)d_in[7];
    const float* bv = (const float*)d_in[8];
    const float* Wo = (const float*)d_in[9];
    const float* bo = (const float*)d_in[10];

    const size_t M1 = (size_t)1024 * 1024;
    // ws layout (56 MB):
    unsigned short* qc  = (unsigned short*)d_ws;   // 4M elems (8 MB)
    unsigned short* kc  = qc + 4 * M1;             // 4M
    unsigned short* vc  = kc + 4 * M1;             // 4M
    unsigned short* Wt  = vc + 4 * M1;             // 3M  [3072][1024]
    unsigned short* Wot = Wt + 3 * M1;             // 1M
    unsigned short* QKV = Wot + M1;                // 12M [4096][3072]
    // aliases after their producers are dead:
    unsigned short* Opart = qc;                    // 8M elems (qc+kc, dead post-QKV)
    float* ML = (float*)vc;                        // 1 MB of vc (dead post-QKV)
    unsigned short* Omg = QKV;                     // 4M elems (QKV dead post-attn)

    dim3 bt(256, 1, 1);
    prepass<<<dim3(7168), bt, 0, stream>>>(q, k, v, Wq, Wk, Wv, Wo,
                                           qc, kc, vc, Wt, Wot);
    gemm_fast<true, 128, 128, 0, 2><<<dim3(768), bt, 0, stream>>>(
        qc, kc, vc, Wt, bq, bk, bv, QKV, 3072);
    attn32_kernel<<<dim3(1024), bt, 0, stream>>>(
        QKV, QKV + 1024, QKV + 2048, Opart, ML, 3072);
    attn_merge<<<dim3(2048), bt, 0, stream>>>(Opart, ML, Omg);
    gemm_fast<false, 128, 64, 1, 2><<<dim3(512), bt, 0, stream>>>(
        Omg, Omg, Omg, Wot, bo, bo, bo, d_out, 1024);
}